// Round 4
// baseline (184.513 us; speedup 1.0000x reference)
//
#include <hip/hip_runtime.h>
#include <hip/hip_bf16.h>

// Colorcal: out[b,c,h,w] = (wcam[cam[b],c] + wident[id[b],c]) * image[b,c,h,w]
//                        + (bcam[cam[b],c] + bident[id[b],c])
// B=32, C=3, H=W=1024, fp32. Streaming op: 768 MB total -> HBM roofline ~128us
// (m13 copy ceiling 6.29 TB/s).
//
// R3 lesson: __builtin_nontemporal stores REGRESSED (160->176us). Harness's
// fillBufferAligned hits 7.0 TB/s with plain stores -> L2 write path is the
// fast path. Keep plain loads/stores; keep compile-time trip count + deep
// unroll for MLP (runtime-trip grid-stride loop leaves ~1 load in flight).

typedef float f32x4 __attribute__((ext_vector_type(4)));

#define HW     (1024 * 1024)
#define HW4    (HW / 4)          // float4 per plane = 262144
#define GRIDX  16                // blocks per plane
#define TPB    256
#define STRIDE (GRIDX * TPB)     // 4096 threads per plane
#define UNROLL 8
#define ITERS  (HW4 / (STRIDE * UNROLL))  // 8 iterations, exact (no tail)

__global__ __launch_bounds__(256) void colorcal_kernel(
    const float* __restrict__ image,
    const int*   __restrict__ camindex,
    const int*   __restrict__ idindex,
    const float* __restrict__ wcam,
    const float* __restrict__ bcam,
    const float* __restrict__ wident,
    const float* __restrict__ bident,
    float* __restrict__ out)
{
    const int plane = blockIdx.y;          // 0..95 == b*3 + c
    const int b     = plane / 3;
    const int c     = plane - b * 3;

    // Wave-uniform scalar gathers: once per block.
    const int cam = camindex[b];
    const int id  = idindex[b];
    const float w    = wcam[cam * 3 + c] + wident[id * 3 + c];
    const float bias = bcam[cam * 3 + c] + bident[id * 3 + c];

    const size_t planeBase = (size_t)plane * HW;
    const f32x4* __restrict__ in4  = reinterpret_cast<const f32x4*>(image + planeBase);
    f32x4*       __restrict__ out4 = reinterpret_cast<f32x4*>(out + planeBase);

    const int tid = blockIdx.x * TPB + threadIdx.x;

    for (int it = 0; it < ITERS; ++it) {
        const int i0 = it * (STRIDE * UNROLL) + tid;
        f32x4 v[UNROLL];
        // 8 independent coalesced 16B loads issued back-to-back -> 8-deep vmcnt.
#pragma unroll
        for (int u = 0; u < UNROLL; ++u)
            v[u] = in4[i0 + u * STRIDE];
#pragma unroll
        for (int u = 0; u < UNROLL; ++u)
            v[u] = v[u] * w + bias;
#pragma unroll
        for (int u = 0; u < UNROLL; ++u)
            out4[i0 + u * STRIDE] = v[u];
    }
}

extern "C" void kernel_launch(void* const* d_in, const int* in_sizes, int n_in,
                              void* d_out, int out_size, void* d_ws, size_t ws_size,
                              hipStream_t stream) {
    const float* image    = (const float*)d_in[0];
    const int*   camindex = (const int*)  d_in[1];
    const int*   idindex  = (const int*)  d_in[2];
    const float* wcam     = (const float*)d_in[3];
    const float* bcam     = (const float*)d_in[4];
    const float* wident   = (const float*)d_in[5];
    const float* bident   = (const float*)d_in[6];
    float* out = (float*)d_out;

    // 96 planes x 16 blocks = 1536 blocks of 256 = 6 blocks/CU, 24 waves/CU.
    dim3 grid(GRIDX, 96, 1);
    dim3 block(TPB, 1, 1);
    colorcal_kernel<<<grid, block, 0, stream>>>(
        image, camindex, idindex, wcam, bcam, wident, bident, out);
}

// Round 5
// 155.529 us; speedup vs baseline: 1.1864x; 1.1864x over previous
//
#include <hip/hip_runtime.h>
#include <hip/hip_bf16.h>

// Colorcal: out[b,c,h,w] = (wcam[cam[b],c] + wident[id[b],c]) * image[b,c,h,w]
//                        + (bcam[cam[b],c] + bident[id[b],c])
// B=32, C=3, H=W=1024, fp32. Streaming: 768 MB -> HBM roofline ~128us @6.3TB/s.
//
// R3: nt stores regressed. R4: 1536-block grid + far-strided unroll-8 regressed
// (VGPR cliff at 64 likely cut residency to 16 waves/CU). R5: big grid (12288
// blocks = self-balancing, 32 waves/CU sustained) + block-contiguous unroll-8
// (small 4KB offsets, one address reg) + __launch_bounds__(256,8) to pin
// VGPR<=64. Each thread: exactly 8 loads, 8 fma, 8 stores. No loop.

typedef float f32x4 __attribute__((ext_vector_type(4)));

#define HW      (1024 * 1024)
#define HW4     (HW / 4)             // 262144 float4 per plane (4 MiB)
#define TPB     256
#define UNROLL  8
#define CHUNK   (TPB * UNROLL)       // 2048 float4 = 32 KiB per block
#define GRIDX   (HW4 / CHUNK)        // 128 blocks per plane

__global__ __launch_bounds__(256, 8) void colorcal_kernel(
    const float* __restrict__ image,
    const int*   __restrict__ camindex,
    const int*   __restrict__ idindex,
    const float* __restrict__ wcam,
    const float* __restrict__ bcam,
    const float* __restrict__ wident,
    const float* __restrict__ bident,
    float* __restrict__ out)
{
    const int plane = blockIdx.y;          // 0..95 == b*3 + c
    const int b     = plane / 3;
    const int c     = plane - b * 3;

    // Wave-uniform scalar gathers: once per block.
    const int cam = camindex[b];
    const int id  = idindex[b];
    const float w    = wcam[cam * 3 + c] + wident[id * 3 + c];
    const float bias = bcam[cam * 3 + c] + bident[id * 3 + c];

    const size_t base = (size_t)plane * HW4 + (size_t)blockIdx.x * CHUNK + threadIdx.x;
    const f32x4* __restrict__ in4  = reinterpret_cast<const f32x4*>(image) + base;
    f32x4*       __restrict__ out4 = reinterpret_cast<f32x4*>(out) + base;

    f32x4 v[UNROLL];
    // 8 independent coalesced 16B loads, 4KB apart -> 8-deep vmcnt, one addr reg.
#pragma unroll
    for (int u = 0; u < UNROLL; ++u)
        v[u] = in4[u * TPB];
#pragma unroll
    for (int u = 0; u < UNROLL; ++u)
        v[u] = v[u] * w + bias;
#pragma unroll
    for (int u = 0; u < UNROLL; ++u)
        out4[u * TPB] = v[u];
}

extern "C" void kernel_launch(void* const* d_in, const int* in_sizes, int n_in,
                              void* d_out, int out_size, void* d_ws, size_t ws_size,
                              hipStream_t stream) {
    const float* image    = (const float*)d_in[0];
    const int*   camindex = (const int*)  d_in[1];
    const int*   idindex  = (const int*)  d_in[2];
    const float* wcam     = (const float*)d_in[3];
    const float* bcam     = (const float*)d_in[4];
    const float* wident   = (const float*)d_in[5];
    const float* bident   = (const float*)d_in[6];
    float* out = (float*)d_out;

    // 96 planes x 128 blocks = 12288 blocks (self-balancing over 256 CUs).
    dim3 grid(GRIDX, 96, 1);
    dim3 block(TPB, 1, 1);
    colorcal_kernel<<<grid, block, 0, stream>>>(
        image, camindex, idindex, wcam, bcam, wident, bident, out);
}

// Round 6
// 152.918 us; speedup vs baseline: 1.2066x; 1.0171x over previous
//
#include <hip/hip_runtime.h>
#include <hip/hip_bf16.h>

// Colorcal: out[b,c,h,w] = (wcam[cam[b],c] + wident[id[b],c]) * image[b,c,h,w]
//                        + (bcam[cam[b],c] + bident[id[b],c])
// B=32, C=3, H=W=1024, fp32. Streaming: 805 MB -> roofline ~128us @6.29 TB/s.
//
// History: R1 grid-stride 160us. R3 nt load+store 176us (nt STORES hurt: skip
// the fast L2 write-allocate path the 6.9TB/s fill kernel uses). R4 small grid
// 184us (VGPR/occupancy cliff). R5 static unroll-8 + 12288 blocks: 155.5us
// (5.18 TB/s). R6 theory: input has ZERO reuse -> nt on LOADS ONLY stops the
// read stream from allocating L2/L3 lines, freeing L2 for store combining.
// Plus wave-contiguous layout: each wave streams 8KiB sequential.

typedef float f32x4 __attribute__((ext_vector_type(4)));

#define HW      (1024 * 1024)
#define HW4     (HW / 4)             // 262144 float4 per plane (4 MiB)
#define TPB     256
#define UNROLL  8
#define CHUNK   (TPB * UNROLL)       // 2048 float4 = 32 KiB per block
#define GRIDX   (HW4 / CHUNK)        // 128 blocks per plane

__global__ __launch_bounds__(256, 8) void colorcal_kernel(
    const float* __restrict__ image,
    const int*   __restrict__ camindex,
    const int*   __restrict__ idindex,
    const float* __restrict__ wcam,
    const float* __restrict__ bcam,
    const float* __restrict__ wident,
    const float* __restrict__ bident,
    float* __restrict__ out)
{
    const int plane = blockIdx.y;          // 0..95 == b*3 + c
    const int b     = plane / 3;
    const int c     = plane - b * 3;

    // Wave-uniform scalar gathers: once per block.
    const int cam = camindex[b];
    const int id  = idindex[b];
    const float w    = wcam[cam * 3 + c] + wident[id * 3 + c];
    const float bias = bcam[cam * 3 + c] + bident[id * 3 + c];

    // Wave-contiguous: wave w owns an 8KiB subchunk; its 8 loads are
    // consecutive 1KiB segments (imm-offset friendly, sequential stream).
    const int wave = threadIdx.x >> 6;
    const int lane = threadIdx.x & 63;
    const size_t base = (size_t)plane * HW4 + (size_t)blockIdx.x * CHUNK
                      + (size_t)wave * (64 * UNROLL) + lane;
    const f32x4* __restrict__ in4  = reinterpret_cast<const f32x4*>(image) + base;
    f32x4*       __restrict__ out4 = reinterpret_cast<f32x4*>(out) + base;

    f32x4 v[UNROLL];
#pragma unroll
    for (int u = 0; u < UNROLL; ++u)
        v[u] = __builtin_nontemporal_load(&in4[u * 64]);  // nt LOAD only: no L2 alloc for the no-reuse read stream
#pragma unroll
    for (int u = 0; u < UNROLL; ++u)
        v[u] = v[u] * w + bias;
#pragma unroll
    for (int u = 0; u < UNROLL; ++u)
        out4[u * 64] = v[u];                              // plain store: keep fast write-allocate path
}

extern "C" void kernel_launch(void* const* d_in, const int* in_sizes, int n_in,
                              void* d_out, int out_size, void* d_ws, size_t ws_size,
                              hipStream_t stream) {
    const float* image    = (const float*)d_in[0];
    const int*   camindex = (const int*)  d_in[1];
    const int*   idindex  = (const int*)  d_in[2];
    const float* wcam     = (const float*)d_in[3];
    const float* bcam     = (const float*)d_in[4];
    const float* wident   = (const float*)d_in[5];
    const float* bident   = (const float*)d_in[6];
    float* out = (float*)d_out;

    // 96 planes x 128 blocks = 12288 blocks (self-balancing over 256 CUs).
    dim3 grid(GRIDX, 96, 1);
    dim3 block(TPB, 1, 1);
    colorcal_kernel<<<grid, block, 0, stream>>>(
        image, camindex, idindex, wcam, bcam, wident, bident, out);
}

// Round 7
// 146.306 us; speedup vs baseline: 1.2611x; 1.0452x over previous
//
#include <hip/hip_runtime.h>
#include <hip/hip_bf16.h>

// Colorcal: out[b,c,h,w] = (wcam[cam[b],c] + wident[id[b],c]) * image[b,c,h,w]
//                        + (bcam[cam[b],c] + bident[id[b],c])
// B=32, C=3, H=W=1024, fp32. Streaming: 805 MB -> roofline ~128us @6.29 TB/s.
//
// History: R1 grid-stride 160us. R3 nt-both + 1536 blocks 176us. R4 plain +
// 1536 blocks 184.5us (grid was the regression, NOT nt). R5 static unroll-8 +
// 12288 blocks 155.5us. R6 + nt LOADS + wave-contiguous 152.9us (5.27 TB/s).
// R7: single-variable A/B vs R6 -- nt STORES too. Output has zero device-side
// reuse; with an 805MB stream >> 256MB L3, write-allocate just thrashes
// L2/L3. If neutral/regress -> R6 is the roofline.

typedef float f32x4 __attribute__((ext_vector_type(4)));

#define HW      (1024 * 1024)
#define HW4     (HW / 4)             // 262144 float4 per plane (4 MiB)
#define TPB     256
#define UNROLL  8
#define CHUNK   (TPB * UNROLL)       // 2048 float4 = 32 KiB per block
#define GRIDX   (HW4 / CHUNK)        // 128 blocks per plane

__global__ __launch_bounds__(256, 8) void colorcal_kernel(
    const float* __restrict__ image,
    const int*   __restrict__ camindex,
    const int*   __restrict__ idindex,
    const float* __restrict__ wcam,
    const float* __restrict__ bcam,
    const float* __restrict__ wident,
    const float* __restrict__ bident,
    float* __restrict__ out)
{
    const int plane = blockIdx.y;          // 0..95 == b*3 + c
    const int b     = plane / 3;
    const int c     = plane - b * 3;

    // Wave-uniform scalar gathers: once per block.
    const int cam = camindex[b];
    const int id  = idindex[b];
    const float w    = wcam[cam * 3 + c] + wident[id * 3 + c];
    const float bias = bcam[cam * 3 + c] + bident[id * 3 + c];

    // Wave-contiguous: each wave owns an 8KiB subchunk; its 8 loads are
    // consecutive 1KiB segments (imm-offset friendly, sequential stream).
    const int wave = threadIdx.x >> 6;
    const int lane = threadIdx.x & 63;
    const size_t base = (size_t)plane * HW4 + (size_t)blockIdx.x * CHUNK
                      + (size_t)wave * (64 * UNROLL) + lane;
    const f32x4* __restrict__ in4  = reinterpret_cast<const f32x4*>(image) + base;
    f32x4*       __restrict__ out4 = reinterpret_cast<f32x4*>(out) + base;

    f32x4 v[UNROLL];
#pragma unroll
    for (int u = 0; u < UNROLL; ++u)
        v[u] = __builtin_nontemporal_load(&in4[u * 64]);   // no L2/L3 alloc: zero-reuse read
#pragma unroll
    for (int u = 0; u < UNROLL; ++u)
        v[u] = v[u] * w + bias;
#pragma unroll
    for (int u = 0; u < UNROLL; ++u)
        __builtin_nontemporal_store(v[u], &out4[u * 64]);  // R7 change: no-alloc write stream
}

extern "C" void kernel_launch(void* const* d_in, const int* in_sizes, int n_in,
                              void* d_out, int out_size, void* d_ws, size_t ws_size,
                              hipStream_t stream) {
    const float* image    = (const float*)d_in[0];
    const int*   camindex = (const int*)  d_in[1];
    const int*   idindex  = (const int*)  d_in[2];
    const float* wcam     = (const float*)d_in[3];
    const float* bcam     = (const float*)d_in[4];
    const float* wident   = (const float*)d_in[5];
    const float* bident   = (const float*)d_in[6];
    float* out = (float*)d_out;

    // 96 planes x 128 blocks = 12288 blocks (self-balancing over 256 CUs).
    dim3 grid(GRIDX, 96, 1);
    dim3 block(TPB, 1, 1);
    colorcal_kernel<<<grid, block, 0, stream>>>(
        image, camindex, idindex, wcam, bcam, wident, bident, out);
}

// Round 8
// 141.514 us; speedup vs baseline: 1.3039x; 1.0339x over previous
//
#include <hip/hip_runtime.h>
#include <hip/hip_bf16.h>

// Colorcal: out[b,c,h,w] = (wcam[cam[b],c] + wident[id[b],c]) * image[b,c,h,w]
//                        + (bcam[cam[b],c] + bident[id[b],c])
// B=32, C=3, H=W=1024, fp32. Streaming: 805 MB -> roofline ~128us @6.29 TB/s.
//
// Ladder: R1 160 (grid-stride) -> R5 155.5 (static unroll-8, 12288 blocks) ->
// R6 152.9 (nt loads + wave-contiguous) -> R7 146.3 (nt stores; 5.50 TB/s).
// R8: UNROLL 8->16. Per-wave bursts double to 16KiB read / 16KiB write,
// halving DRAM read<->write turnarounds per byte. Occupancy drops to ~20
// waves/CU but in-flight bytes are 28x the latency-BW product, so TLP loss
// should be free. If neutral: R7 structure is the mixed-stream roofline.

typedef float f32x4 __attribute__((ext_vector_type(4)));

#define HW      (1024 * 1024)
#define HW4     (HW / 4)             // 262144 float4 per plane (4 MiB)
#define TPB     256
#define UNROLL  16
#define CHUNK   (TPB * UNROLL)       // 4096 float4 = 64 KiB per block
#define GRIDX   (HW4 / CHUNK)        // 64 blocks per plane

__global__ __launch_bounds__(256, 4) void colorcal_kernel(
    const float* __restrict__ image,
    const int*   __restrict__ camindex,
    const int*   __restrict__ idindex,
    const float* __restrict__ wcam,
    const float* __restrict__ bcam,
    const float* __restrict__ wident,
    const float* __restrict__ bident,
    float* __restrict__ out)
{
    const int plane = blockIdx.y;          // 0..95 == b*3 + c
    const int b     = plane / 3;
    const int c     = plane - b * 3;

    // Wave-uniform scalar gathers: once per block.
    const int cam = camindex[b];
    const int id  = idindex[b];
    const float w    = wcam[cam * 3 + c] + wident[id * 3 + c];
    const float bias = bcam[cam * 3 + c] + bident[id * 3 + c];

    // Wave-contiguous: each wave owns a 16KiB subchunk; its 16 loads are
    // consecutive 1KiB segments (sequential stream per wave).
    const int wave = threadIdx.x >> 6;
    const int lane = threadIdx.x & 63;
    const size_t base = (size_t)plane * HW4 + (size_t)blockIdx.x * CHUNK
                      + (size_t)wave * (64 * UNROLL) + lane;
    const f32x4* __restrict__ in4  = reinterpret_cast<const f32x4*>(image) + base;
    f32x4*       __restrict__ out4 = reinterpret_cast<f32x4*>(out) + base;

    f32x4 v[UNROLL];
#pragma unroll
    for (int u = 0; u < UNROLL; ++u)
        v[u] = __builtin_nontemporal_load(&in4[u * 64]);   // 16KiB read burst/wave
#pragma unroll
    for (int u = 0; u < UNROLL; ++u)
        v[u] = v[u] * w + bias;
#pragma unroll
    for (int u = 0; u < UNROLL; ++u)
        __builtin_nontemporal_store(v[u], &out4[u * 64]);  // 16KiB write burst/wave
}

extern "C" void kernel_launch(void* const* d_in, const int* in_sizes, int n_in,
                              void* d_out, int out_size, void* d_ws, size_t ws_size,
                              hipStream_t stream) {
    const float* image    = (const float*)d_in[0];
    const int*   camindex = (const int*)  d_in[1];
    const int*   idindex  = (const int*)  d_in[2];
    const float* wcam     = (const float*)d_in[3];
    const float* bcam     = (const float*)d_in[4];
    const float* wident   = (const float*)d_in[5];
    const float* bident   = (const float*)d_in[6];
    float* out = (float*)d_out;

    // 96 planes x 64 blocks = 6144 blocks.
    dim3 grid(GRIDX, 96, 1);
    dim3 block(TPB, 1, 1);
    colorcal_kernel<<<grid, block, 0, stream>>>(
        image, camindex, idindex, wcam, bcam, wident, bident, out);
}

// Round 9
// 140.378 us; speedup vs baseline: 1.3144x; 1.0081x over previous
//
#include <hip/hip_runtime.h>
#include <hip/hip_bf16.h>

// Colorcal: out[b,c,h,w] = (wcam[cam[b],c] + wident[id[b],c]) * image[b,c,h,w]
//                        + (bcam[cam[b],c] + bident[id[b],c])
// B=32, C=3, H=W=1024, fp32. Streaming: 805 MB -> roofline ~128us @6.29 TB/s.
//
// Ladder: R1 160 (grid-stride) -> R5 155.5 (static unroll-8, 12288 blocks) ->
// R6 152.9 (nt loads + wave-contiguous) -> R7 146.3 (nt stores) ->
// R8 141.5 (UNROLL=16, 16KiB bursts; 5.69 TB/s = 90.5% of copy ceiling).
// R9: UNROLL 16->32 (32KiB read burst / 32KiB write burst per wave, halving
// DRAM direction turnarounds per byte again). ~155-170 VGPR -> 12 waves/CU;
// in-flight bytes still ~40x latency-BW product. If neutral -> R8 roofline.

typedef float f32x4 __attribute__((ext_vector_type(4)));

#define HW      (1024 * 1024)
#define HW4     (HW / 4)             // 262144 float4 per plane (4 MiB)
#define TPB     256
#define UNROLL  32
#define CHUNK   (TPB * UNROLL)       // 8192 float4 = 128 KiB per block
#define GRIDX   (HW4 / CHUNK)        // 32 blocks per plane

__global__ __launch_bounds__(256, 3) void colorcal_kernel(
    const float* __restrict__ image,
    const int*   __restrict__ camindex,
    const int*   __restrict__ idindex,
    const float* __restrict__ wcam,
    const float* __restrict__ bcam,
    const float* __restrict__ wident,
    const float* __restrict__ bident,
    float* __restrict__ out)
{
    const int plane = blockIdx.y;          // 0..95 == b*3 + c
    const int b     = plane / 3;
    const int c     = plane - b * 3;

    // Wave-uniform scalar gathers: once per block.
    const int cam = camindex[b];
    const int id  = idindex[b];
    const float w    = wcam[cam * 3 + c] + wident[id * 3 + c];
    const float bias = bcam[cam * 3 + c] + bident[id * 3 + c];

    // Wave-contiguous: each wave owns a 32KiB subchunk; its 32 loads are
    // consecutive 1KiB segments (sequential stream per wave).
    const int wave = threadIdx.x >> 6;
    const int lane = threadIdx.x & 63;
    const size_t base = (size_t)plane * HW4 + (size_t)blockIdx.x * CHUNK
                      + (size_t)wave * (64 * UNROLL) + lane;
    const f32x4* __restrict__ in4  = reinterpret_cast<const f32x4*>(image) + base;
    f32x4*       __restrict__ out4 = reinterpret_cast<f32x4*>(out) + base;

    f32x4 v[UNROLL];
#pragma unroll
    for (int u = 0; u < UNROLL; ++u)
        v[u] = __builtin_nontemporal_load(&in4[u * 64]);   // 32KiB read burst/wave
#pragma unroll
    for (int u = 0; u < UNROLL; ++u)
        v[u] = v[u] * w + bias;
#pragma unroll
    for (int u = 0; u < UNROLL; ++u)
        __builtin_nontemporal_store(v[u], &out4[u * 64]);  // 32KiB write burst/wave
}

extern "C" void kernel_launch(void* const* d_in, const int* in_sizes, int n_in,
                              void* d_out, int out_size, void* d_ws, size_t ws_size,
                              hipStream_t stream) {
    const float* image    = (const float*)d_in[0];
    const int*   camindex = (const int*)  d_in[1];
    const int*   idindex  = (const int*)  d_in[2];
    const float* wcam     = (const float*)d_in[3];
    const float* bcam     = (const float*)d_in[4];
    const float* wident   = (const float*)d_in[5];
    const float* bident   = (const float*)d_in[6];
    float* out = (float*)d_out;

    // 96 planes x 32 blocks = 3072 blocks.
    dim3 grid(GRIDX, 96, 1);
    dim3 block(TPB, 1, 1);
    colorcal_kernel<<<grid, block, 0, stream>>>(
        image, camindex, idindex, wcam, bcam, wident, bident, out);
}